// Round 1
// baseline (368.749 us; speedup 1.0000x reference)
//
#include <hip/hip_runtime.h>
#include <math.h>

#define NB  64
#define NT  512
#define ND  1024
#define NVT 6
#define NVY 20
#define TYPE_PAD_V 19
#define NE  2048

// ---------------- K0: transpose W_type into ws, zero d_out ----------------
__global__ __launch_bounds__(256) void k0_prep(const float* __restrict__ W_type,
                                               float* __restrict__ WtT,
                                               float* __restrict__ out) {
    if (blockIdx.x == 0 && threadIdx.x < NB) out[threadIdx.x] = 0.0f;
    int tid = blockIdx.x * 256 + threadIdx.x;
    int stride = gridDim.x * 256;
    for (int i = tid; i < NVY * ND; i += stride) {
        int v = i >> 10;        // 0..19
        int d = i & (ND - 1);   // 0..1023
        WtT[i] = W_type[d * NVY + v];
    }
}

// ---------------- K1: tag_feats = H @ W_tag + b_tag ----------------
// Quarter-wave (16 lanes) per row; W_tag^T staged in LDS (broadcast reads).
__global__ __launch_bounds__(256) void k1_tagfeats(const float* __restrict__ H,
                                                   const float* __restrict__ W_tag,
                                                   const float* __restrict__ b_tag,
                                                   float* __restrict__ tag_feats) {
    __shared__ float wlds[NVT][ND];   // 24 KB, transposed
    for (int i = threadIdx.x; i < ND * NVT; i += 256) {
        int d = i / NVT, v = i % NVT;  // i = d*6+v (W_tag row-major D x 6)
        wlds[v][d] = W_tag[i];
    }
    __syncthreads();
    float bt[NVT];
#pragma unroll
    for (int v = 0; v < NVT; ++v) bt[v] = b_tag[v];

    const int lane = threadIdx.x & 63;
    const int wid  = threadIdx.x >> 6;   // wave 0..3
    const int qw   = lane >> 4;          // quarter 0..3
    const int ql   = lane & 15;          // lane in quarter
    const int rowBase = blockIdx.x * 32; // 1024 blocks * 32 rows = 32768

#pragma unroll
    for (int it = 0; it < 2; ++it) {
        const int r = rowBase + it * 16 + wid * 4 + qw;
        const float4* hrow = (const float4*)(H + (size_t)r * ND);
        float acc[NVT] = {0.f, 0.f, 0.f, 0.f, 0.f, 0.f};
#pragma unroll
        for (int k = 0; k < 16; ++k) {
            float4 h = hrow[ql + 16 * k];
#pragma unroll
            for (int v = 0; v < NVT; ++v) {
                float4 w = ((const float4*)&wlds[v][0])[ql + 16 * k];
                acc[v] += h.x * w.x + h.y * w.y + h.z * w.z + h.w * w.w;
            }
        }
#pragma unroll
        for (int v = 0; v < NVT; ++v) {
#pragma unroll
            for (int off = 8; off >= 1; off >>= 1)
                acc[v] += __shfl_xor(acc[v], off);
        }
#pragma unroll
        for (int v = 0; v < NVT; ++v)
            if (ql == v) tag_feats[(size_t)r * NVT + v] = acc[v] + bt[v];
    }
}

// ---------------- K23: fused CRF (blocks 0..63) + entities (blocks 64..) ----------------
__global__ __launch_bounds__(64) void k23_crf_ent(
    const float* __restrict__ tag_feats,
    const float* __restrict__ WtT,
    const float* __restrict__ H,
    const float* __restrict__ b_type,
    const float* __restrict__ crf_start,
    const float* __restrict__ crf_end,
    const float* __restrict__ crf_trans,
    const int* __restrict__ tag_ids,
    const int* __restrict__ seq_lens,
    const int* __restrict__ ent_sid,
    const int* __restrict__ ent_st,
    const int* __restrict__ ent_en,
    const int* __restrict__ ent_ty,
    float* __restrict__ out) {
    __shared__ float4 sbuf4[NT * NVT / 4];  // 12 KB: tag_feats for one sample
    __shared__ int stag[NT];                // 2 KB
    const int lane = threadIdx.x;

    if (blockIdx.x < NB) {
        // ----------- CRF path: one block (1 wave) per sample -----------
        const int b = blockIdx.x;
        const int L = seq_lens[b];
        const float4* src = (const float4*)(tag_feats + (size_t)b * NT * NVT);
        for (int i = lane; i < NT * NVT / 4; i += 64) sbuf4[i] = src[i];
        for (int i = lane; i < NT; i += 64) stag[i] = tag_ids[b * NT + i];
        __syncthreads();
        const float* sfeat = (const float*)sbuf4;

        // gold path score (emit + transition terms), lanes parallel over t
        float g = 0.0f;
#pragma unroll
        for (int k = 0; k < NT / 64; ++k) {
            int t = lane + 64 * k;
            if (t < L) {
                int tg = stag[t];
                g += sfeat[t * NVT + tg];
                if (t >= 1) g += crf_trans[stag[t - 1] * NVT + tg];
            }
        }
#pragma unroll
        for (int off = 32; off >= 1; off >>= 1) g += __shfl_xor(g, off);
        g += crf_start[stag[0]] + crf_end[stag[L - 1]];

        // forward algorithm (replicated across lanes; latency-bound chain)
        float tr[NVT][NVT];
#pragma unroll
        for (int i = 0; i < NVT; ++i)
#pragma unroll
            for (int j = 0; j < NVT; ++j) tr[i][j] = crf_trans[i * NVT + j];
        float cend[NVT];
#pragma unroll
        for (int j = 0; j < NVT; ++j) cend[j] = crf_end[j];
        float a[NVT];
#pragma unroll
        for (int j = 0; j < NVT; ++j) a[j] = crf_start[j] + sfeat[j];

        for (int t = 1; t < L; ++t) {
            float e[NVT], na[NVT];
#pragma unroll
            for (int j = 0; j < NVT; ++j) e[j] = sfeat[t * NVT + j];
#pragma unroll
            for (int j = 0; j < NVT; ++j) {
                float s0 = a[0] + tr[0][j];
                float s1 = a[1] + tr[1][j];
                float s2 = a[2] + tr[2][j];
                float s3 = a[3] + tr[3][j];
                float s4 = a[4] + tr[4][j];
                float s5 = a[5] + tr[5][j];
                float m = fmaxf(fmaxf(fmaxf(s0, s1), fmaxf(s2, s3)), fmaxf(s4, s5));
                float se = __expf(s0 - m) + __expf(s1 - m) + __expf(s2 - m)
                         + __expf(s3 - m) + __expf(s4 - m) + __expf(s5 - m);
                na[j] = m + __logf(se) + e[j];
            }
#pragma unroll
            for (int j = 0; j < NVT; ++j) a[j] = na[j];
        }
        // logZ
        float z0 = a[0] + cend[0], z1 = a[1] + cend[1], z2 = a[2] + cend[2];
        float z3 = a[3] + cend[3], z4 = a[4] + cend[4], z5 = a[5] + cend[5];
        float m = fmaxf(fmaxf(fmaxf(z0, z1), fmaxf(z2, z3)), fmaxf(z4, z5));
        float se = __expf(z0 - m) + __expf(z1 - m) + __expf(z2 - m)
                 + __expf(z3 - m) + __expf(z4 - m) + __expf(z5 - m);
        float logZ = m + __logf(se);
        if (lane == 0) atomicAdd(&out[b], logZ - g);
    } else {
        // ----------- entity path: one wave per entity -----------
        const int e  = blockIdx.x - NB;
        const int b  = ent_sid[e];
        const int s  = ent_st[e];
        const int en = ent_en[e];
        const int ty = ent_ty[e];
        float4 sv[4];
#pragma unroll
        for (int k = 0; k < 4; ++k) { sv[k].x = 0.f; sv[k].y = 0.f; sv[k].z = 0.f; sv[k].w = 0.f; }
        for (int t = s; t < en; ++t) {
            const float4* hr = (const float4*)(H + ((size_t)b * NT + t) * ND);
#pragma unroll
            for (int k = 0; k < 4; ++k) {
                float4 h = hr[lane + 64 * k];
                sv[k].x += h.x; sv[k].y += h.y; sv[k].z += h.z; sv[k].w += h.w;
            }
        }
        const float inv = 1.0f / (float)(en - s);
        float f[NVY];
#pragma unroll
        for (int v = 0; v < NVY; ++v) {
            const float4* wv = (const float4*)(WtT + v * ND);
            float p = 0.0f;
#pragma unroll
            for (int k = 0; k < 4; ++k) {
                float4 w = wv[lane + 64 * k];
                p += sv[k].x * w.x + sv[k].y * w.y + sv[k].z * w.z + sv[k].w * w.w;
            }
#pragma unroll
            for (int off = 32; off >= 1; off >>= 1) p += __shfl_xor(p, off);
            f[v] = p * inv + b_type[v];
        }
        float mx = -3.0e38f;
#pragma unroll
        for (int v = 0; v < NVY; ++v) mx = fmaxf(mx, f[v]);
        float sum = 0.0f, goldf = 0.0f;
#pragma unroll
        for (int v = 0; v < NVY; ++v) {
            sum += __expf(f[v] - mx);
            if (v == ty) goldf = f[v];
        }
        float lse = mx + __logf(sum);
        if (ty != TYPE_PAD_V && lane == 0) atomicAdd(&out[b], lse - goldf);
    }
}

extern "C" void kernel_launch(void* const* d_in, const int* in_sizes, int n_in,
                              void* d_out, int out_size, void* d_ws, size_t ws_size,
                              hipStream_t stream) {
    const float* H         = (const float*)d_in[0];
    const float* W_tag     = (const float*)d_in[1];
    const float* b_tag     = (const float*)d_in[2];
    const float* W_type    = (const float*)d_in[3];
    const float* b_type    = (const float*)d_in[4];
    const float* crf_start = (const float*)d_in[5];
    const float* crf_end   = (const float*)d_in[6];
    const float* crf_trans = (const float*)d_in[7];
    const int* tag_ids     = (const int*)d_in[8];
    const int* seq_lens    = (const int*)d_in[9];
    const int* ent_sid     = (const int*)d_in[10];
    const int* ent_st      = (const int*)d_in[11];
    const int* ent_en      = (const int*)d_in[12];
    const int* ent_ty      = (const int*)d_in[13];
    float* out = (float*)d_out;
    float* ws  = (float*)d_ws;
    float* tag_feats = ws;                              // 196608 floats
    float* WtT       = ws + (size_t)NB * NT * NVT;      // 20480 floats

    hipLaunchKernelGGL(k0_prep, dim3(32), dim3(256), 0, stream, W_type, WtT, out);
    hipLaunchKernelGGL(k1_tagfeats, dim3(1024), dim3(256), 0, stream, H, W_tag, b_tag, tag_feats);
    hipLaunchKernelGGL(k23_crf_ent, dim3(NB + NE), dim3(64), 0, stream,
                       tag_feats, WtT, H, b_type, crf_start, crf_end, crf_trans,
                       tag_ids, seq_lens, ent_sid, ent_st, ent_en, ent_ty, out);
}

// Round 2
// 177.543 us; speedup vs baseline: 2.0770x; 2.0770x over previous
//
#include <hip/hip_runtime.h>
#include <math.h>

#define NB  64
#define NT  512
#define ND  1024
#define NVT 6
#define NVY 20
#define TYPE_PAD_V 19
#define NE  2048
#define LOG2E 1.44269504088896340736f
#define LN2   0.69314718055994530942f

typedef float v2f __attribute__((ext_vector_type(2)));

// ---------------- K0: transpose W_type into ws, zero d_out ----------------
__global__ __launch_bounds__(256) void k0_prep(const float* __restrict__ W_type,
                                               float* __restrict__ WtT,
                                               float* __restrict__ out) {
    if (blockIdx.x == 0 && threadIdx.x < NB) out[threadIdx.x] = 0.0f;
    int tid = blockIdx.x * 256 + threadIdx.x;
    int stride = gridDim.x * 256;
    for (int i = tid; i < NVY * ND; i += stride) {
        int v = i >> 10;        // 0..19
        int d = i & (ND - 1);   // 0..1023
        WtT[i] = W_type[d * NVY + v];
    }
}

// ---------------- K1: featsT[t][b][j] = (H @ W_tag + b_tag) transposed ----------------
__global__ __launch_bounds__(256) void k1_tagfeats(const float* __restrict__ H,
                                                   const float* __restrict__ W_tag,
                                                   const float* __restrict__ b_tag,
                                                   float* __restrict__ featsT) {
    __shared__ float wlds[NVT][ND];   // 24 KB, transposed
    for (int i = threadIdx.x; i < ND * NVT; i += 256) {
        int d = i / NVT, v = i % NVT;  // W_tag row-major D x 6
        wlds[v][d] = W_tag[i];
    }
    __syncthreads();
    float bt[NVT];
#pragma unroll
    for (int v = 0; v < NVT; ++v) bt[v] = b_tag[v];

    const int lane = threadIdx.x & 63;
    const int wid  = threadIdx.x >> 6;   // wave 0..3
    const int qw   = lane >> 4;          // quarter 0..3
    const int ql   = lane & 15;          // lane in quarter
    const int rowBase = blockIdx.x * 32; // 1024 blocks * 32 rows = 32768

#pragma unroll
    for (int it = 0; it < 2; ++it) {
        const int r = rowBase + it * 16 + wid * 4 + qw;
        const float4* hrow = (const float4*)(H + (size_t)r * ND);
        float acc[NVT] = {0.f, 0.f, 0.f, 0.f, 0.f, 0.f};
#pragma unroll
        for (int k = 0; k < 16; ++k) {
            float4 h = hrow[ql + 16 * k];
#pragma unroll
            for (int v = 0; v < NVT; ++v) {
                float4 w = ((const float4*)&wlds[v][0])[ql + 16 * k];
                acc[v] += h.x * w.x + h.y * w.y + h.z * w.z + h.w * w.w;
            }
        }
#pragma unroll
        for (int v = 0; v < NVT; ++v) {
#pragma unroll
            for (int off = 8; off >= 1; off >>= 1)
                acc[v] += __shfl_xor(acc[v], off);
        }
        const int bb = r >> 9;          // sample
        const int tt = r & (NT - 1);    // time
        float* dst = featsT + ((size_t)tt * NB + bb) * NVT;
#pragma unroll
        for (int v = 0; v < NVT; ++v)
            if (ql == v) dst[v] = acc[v] + bt[v];
    }
}

// ---------------- K2: fused scan(block 0) + gold(1..64) + entities(65..) ----------------
#define LOAD_E(dst, tt) do {                                              \
    const v2f* _p = (const v2f*)(base + (size_t)(tt) * (NB * NVT));       \
    v2f _x0 = _p[0], _x1 = _p[1], _x2 = _p[2];                            \
    dst[0] = _x0.x; dst[1] = _x0.y; dst[2] = _x1.x;                       \
    dst[3] = _x1.y; dst[4] = _x2.x; dst[5] = _x2.y;                       \
} while (0)

#define SCAN_STEP(t, e) do {                                              \
    float m = fmaxf(fmaxf(fmaxf(a[0], a[1]), fmaxf(a[2], a[3])),          \
                    fmaxf(a[4], a[5]));                                   \
    float mc = m * LOG2E;                                                 \
    float p6[NVT];                                                        \
    _Pragma("unroll")                                                     \
    for (int i = 0; i < NVT; ++i)                                         \
        p6[i] = __builtin_amdgcn_exp2f(__builtin_fmaf(a[i], LOG2E, -mc)); \
    v2f s2[3];                                                            \
    _Pragma("unroll")                                                     \
    for (int jh = 0; jh < 3; ++jh)                                        \
        s2[jh] = ((v2f){p6[0], p6[0]}) * F2[0][jh];                       \
    _Pragma("unroll")                                                     \
    for (int i = 1; i < NVT; ++i) {                                       \
        _Pragma("unroll")                                                 \
        for (int jh = 0; jh < 3; ++jh)                                    \
            s2[jh] = __builtin_elementwise_fma((v2f){p6[i], p6[i]},       \
                                               F2[i][jh], s2[jh]);        \
    }                                                                     \
    bool ok = (t) < L;                                                    \
    _Pragma("unroll")                                                     \
    for (int jh = 0; jh < 3; ++jh) {                                      \
        float n0 = __builtin_fmaf(__builtin_amdgcn_logf(s2[jh].x), LN2, m)\
                   + e[2 * jh];                                           \
        float n1 = __builtin_fmaf(__builtin_amdgcn_logf(s2[jh].y), LN2, m)\
                   + e[2 * jh + 1];                                       \
        a[2 * jh]     = ok ? n0 : a[2 * jh];                              \
        a[2 * jh + 1] = ok ? n1 : a[2 * jh + 1];                          \
    }                                                                     \
} while (0)

__global__ __launch_bounds__(64) void k2_fused(
    const float* __restrict__ featsT,
    const float* __restrict__ WtT,
    const float* __restrict__ H,
    const float* __restrict__ b_type,
    const float* __restrict__ crf_start,
    const float* __restrict__ crf_end,
    const float* __restrict__ crf_trans,
    const int* __restrict__ tag_ids,
    const int* __restrict__ seq_lens,
    const int* __restrict__ ent_sid,
    const int* __restrict__ ent_st,
    const int* __restrict__ ent_en,
    const int* __restrict__ ent_ty,
    float* __restrict__ out) {
    __shared__ int stag[NT];            // gold path
    __shared__ float trL[NVT * NVT];
    const int lane = threadIdx.x;

    if (blockIdx.x == 0) {
        // ---------- forward scan: lane = sample, one wave for the whole batch ----
        const int b = lane;
        const int L = seq_lens[b];
        v2f F2[NVT][3];
#pragma unroll
        for (int i = 0; i < NVT; ++i) {
#pragma unroll
            for (int jh = 0; jh < 3; ++jh) {
                F2[i][jh].x = __builtin_amdgcn_exp2f(crf_trans[i * NVT + 2 * jh] * LOG2E);
                F2[i][jh].y = __builtin_amdgcn_exp2f(crf_trans[i * NVT + 2 * jh + 1] * LOG2E);
            }
        }
        const float* base = featsT + b * NVT;
        float a[NVT];
#pragma unroll
        for (int j = 0; j < NVT; ++j) a[j] = crf_start[j] + base[j];

        float e[NVT], en[NVT];
        LOAD_E(e, 1);
        for (int t = 1; t < NT - 1; ++t) {
            LOAD_E(en, t + 1);           // prefetch next step (coalesced 1536 B)
            SCAN_STEP(t, e);
#pragma unroll
            for (int j = 0; j < NVT; ++j) e[j] = en[j];
        }
        SCAN_STEP(NT - 1, e);

        float z[NVT];
#pragma unroll
        for (int j = 0; j < NVT; ++j) z[j] = a[j] + crf_end[j];
        float m = fmaxf(fmaxf(fmaxf(z[0], z[1]), fmaxf(z[2], z[3])), fmaxf(z[4], z[5]));
        float sum = 0.0f;
#pragma unroll
        for (int j = 0; j < NVT; ++j)
            sum += __builtin_amdgcn_exp2f((z[j] - m) * LOG2E);
        float logZ = __builtin_fmaf(__builtin_amdgcn_logf(sum), LN2, m);
        atomicAdd(&out[b], logZ);
    } else if (blockIdx.x <= NB) {
        // ---------- gold path score: one wave per sample, lanes over t ----------
        const int b = blockIdx.x - 1;
        for (int i = lane; i < NT; i += 64) stag[i] = tag_ids[b * NT + i];
        if (lane < NVT * NVT) trL[lane] = crf_trans[lane];
        __syncthreads();
        const int L = seq_lens[b];
        float g = 0.0f;
#pragma unroll
        for (int k = 0; k < NT / 64; ++k) {
            int t = lane + 64 * k;
            if (t < L) {
                int tg = stag[t];
                g += featsT[((size_t)t * NB + b) * NVT + tg];
                if (t >= 1) g += trL[stag[t - 1] * NVT + tg];
            }
        }
#pragma unroll
        for (int off = 32; off >= 1; off >>= 1) g += __shfl_xor(g, off);
        if (lane == 0)
            atomicAdd(&out[b], -(g + crf_start[stag[0]] + crf_end[stag[L - 1]]));
    } else {
        // ---------- entity path: one wave per entity ----------
        const int e  = blockIdx.x - NB - 1;
        const int b  = ent_sid[e];
        const int s  = ent_st[e];
        const int en = ent_en[e];
        const int ty = ent_ty[e];
        float4 sv[4];
#pragma unroll
        for (int k = 0; k < 4; ++k) { sv[k].x = 0.f; sv[k].y = 0.f; sv[k].z = 0.f; sv[k].w = 0.f; }
        for (int t = s; t < en; ++t) {
            const float4* hr = (const float4*)(H + ((size_t)b * NT + t) * ND);
#pragma unroll
            for (int k = 0; k < 4; ++k) {
                float4 h = hr[lane + 64 * k];
                sv[k].x += h.x; sv[k].y += h.y; sv[k].z += h.z; sv[k].w += h.w;
            }
        }
        const float inv = 1.0f / (float)(en - s);
        float f[NVY];
#pragma unroll
        for (int v = 0; v < NVY; ++v) {
            const float4* wv = (const float4*)(WtT + v * ND);
            float p = 0.0f;
#pragma unroll
            for (int k = 0; k < 4; ++k) {
                float4 w = wv[lane + 64 * k];
                p += sv[k].x * w.x + sv[k].y * w.y + sv[k].z * w.z + sv[k].w * w.w;
            }
#pragma unroll
            for (int off = 32; off >= 1; off >>= 1) p += __shfl_xor(p, off);
            f[v] = p * inv + b_type[v];
        }
        float mx = -3.0e38f;
#pragma unroll
        for (int v = 0; v < NVY; ++v) mx = fmaxf(mx, f[v]);
        float sum = 0.0f, goldf = 0.0f;
#pragma unroll
        for (int v = 0; v < NVY; ++v) {
            sum += __expf(f[v] - mx);
            if (v == ty) goldf = f[v];
        }
        float lse = mx + __logf(sum);
        if (ty != TYPE_PAD_V && lane == 0) atomicAdd(&out[b], lse - goldf);
    }
}

extern "C" void kernel_launch(void* const* d_in, const int* in_sizes, int n_in,
                              void* d_out, int out_size, void* d_ws, size_t ws_size,
                              hipStream_t stream) {
    const float* H         = (const float*)d_in[0];
    const float* W_tag     = (const float*)d_in[1];
    const float* b_tag     = (const float*)d_in[2];
    const float* W_type    = (const float*)d_in[3];
    const float* b_type    = (const float*)d_in[4];
    const float* crf_start = (const float*)d_in[5];
    const float* crf_end   = (const float*)d_in[6];
    const float* crf_trans = (const float*)d_in[7];
    const int* tag_ids     = (const int*)d_in[8];
    const int* seq_lens    = (const int*)d_in[9];
    const int* ent_sid     = (const int*)d_in[10];
    const int* ent_st      = (const int*)d_in[11];
    const int* ent_en      = (const int*)d_in[12];
    const int* ent_ty      = (const int*)d_in[13];
    float* out = (float*)d_out;
    float* ws  = (float*)d_ws;
    float* featsT = ws;                              // [T][B][6] = 196608 floats
    float* WtT    = ws + (size_t)NB * NT * NVT;      // [20][1024] = 20480 floats

    hipLaunchKernelGGL(k0_prep, dim3(32), dim3(256), 0, stream, W_type, WtT, out);
    hipLaunchKernelGGL(k1_tagfeats, dim3(1024), dim3(256), 0, stream, H, W_tag, b_tag, featsT);
    hipLaunchKernelGGL(k2_fused, dim3(1 + NB + NE), dim3(64), 0, stream,
                       featsT, WtT, H, b_type, crf_start, crf_end, crf_trans,
                       tag_ids, seq_lens, ent_sid, ent_st, ent_en, ent_ty, out);
}

// Round 3
// 126.513 us; speedup vs baseline: 2.9147x; 1.4034x over previous
//
#include <hip/hip_runtime.h>
#include <math.h>

#define NB  64
#define NT  512
#define ND  1024
#define NVT 6
#define NVY 20
#define TYPE_PAD_V 19
#define NE  2048
#define LOG2E 1.44269504088896340736f
#define LN2   0.69314718055994530942f
#define PDEPTH 16

typedef float v2f __attribute__((ext_vector_type(2)));

// ---------------- K0: transpose W_type into ws, zero d_out ----------------
__global__ __launch_bounds__(256) void k0_prep(const float* __restrict__ W_type,
                                               float* __restrict__ WtT,
                                               float* __restrict__ out) {
    if (blockIdx.x == 0 && threadIdx.x < NB) out[threadIdx.x] = 0.0f;
    int tid = blockIdx.x * 256 + threadIdx.x;
    int stride = gridDim.x * 256;
    for (int i = tid; i < NVY * ND; i += stride) {
        int v = i >> 10;        // 0..19
        int d = i & (ND - 1);   // 0..1023
        WtT[i] = W_type[d * NVY + v];
    }
}

// ---------------- K1: featsT[t][b][j] = (H @ W_tag + b_tag) transposed ----------------
__global__ __launch_bounds__(256) void k1_tagfeats(const float* __restrict__ H,
                                                   const float* __restrict__ W_tag,
                                                   const float* __restrict__ b_tag,
                                                   float* __restrict__ featsT) {
    __shared__ float wlds[NVT][ND];   // 24 KB, transposed
    for (int i = threadIdx.x; i < ND * NVT; i += 256) {
        int d = i / NVT, v = i % NVT;  // W_tag row-major D x 6
        wlds[v][d] = W_tag[i];
    }
    __syncthreads();
    float bt[NVT];
#pragma unroll
    for (int v = 0; v < NVT; ++v) bt[v] = b_tag[v];

    const int lane = threadIdx.x & 63;
    const int wid  = threadIdx.x >> 6;   // wave 0..3
    const int qw   = lane >> 4;          // quarter 0..3
    const int ql   = lane & 15;          // lane in quarter
    const int rowBase = blockIdx.x * 32; // 1024 blocks * 32 rows = 32768

#pragma unroll
    for (int it = 0; it < 2; ++it) {
        const int r = rowBase + it * 16 + wid * 4 + qw;
        const float4* hrow = (const float4*)(H + (size_t)r * ND);
        float acc[NVT] = {0.f, 0.f, 0.f, 0.f, 0.f, 0.f};
#pragma unroll
        for (int k = 0; k < 16; ++k) {
            float4 h = hrow[ql + 16 * k];
#pragma unroll
            for (int v = 0; v < NVT; ++v) {
                float4 w = ((const float4*)&wlds[v][0])[ql + 16 * k];
                acc[v] += h.x * w.x + h.y * w.y + h.z * w.z + h.w * w.w;
            }
        }
#pragma unroll
        for (int v = 0; v < NVT; ++v) {
#pragma unroll
            for (int off = 8; off >= 1; off >>= 1)
                acc[v] += __shfl_xor(acc[v], off);
        }
        const int bb = r >> 9;          // sample
        const int tt = r & (NT - 1);    // time
        float* dst = featsT + ((size_t)tt * NB + bb) * NVT;
#pragma unroll
        for (int v = 0; v < NVT; ++v)
            if (ql == v) dst[v] = acc[v] + bt[v];
    }
}

// ---------------- K2: fused scan(block 0) + gold(1..64) + entities(65..) ----------------
__global__ __launch_bounds__(64) void k2_fused(
    const float* __restrict__ featsT,
    const float* __restrict__ WtT,
    const float* __restrict__ H,
    const float* __restrict__ b_type,
    const float* __restrict__ crf_start,
    const float* __restrict__ crf_end,
    const float* __restrict__ crf_trans,
    const int* __restrict__ tag_ids,
    const int* __restrict__ seq_lens,
    const int* __restrict__ ent_sid,
    const int* __restrict__ ent_st,
    const int* __restrict__ ent_en,
    const int* __restrict__ ent_ty,
    float* __restrict__ out) {
    __shared__ int stag[NT];            // gold path
    __shared__ float trL[NVT * NVT];
    const int lane = threadIdx.x;

    if (blockIdx.x == 0) {
        // ---------- forward scan: lane = sample, one wave for the whole batch ----
        const int b = lane;
        const int L = seq_lens[b];
        v2f F2[NVT][3];
#pragma unroll
        for (int i = 0; i < NVT; ++i) {
#pragma unroll
            for (int jh = 0; jh < 3; ++jh) {
                F2[i][jh].x = __builtin_amdgcn_exp2f(crf_trans[i * NVT + 2 * jh] * LOG2E);
                F2[i][jh].y = __builtin_amdgcn_exp2f(crf_trans[i * NVT + 2 * jh + 1] * LOG2E);
            }
        }
        const float* base = featsT + b * NVT;
        float a[NVT];
#pragma unroll
        for (int j = 0; j < NVT; ++j) a[j] = crf_start[j] + base[j];
        float m_use = fmaxf(fmaxf(fmaxf(a[0], a[1]), a[2]),
                            fmaxf(fmaxf(a[3], a[4]), a[5]));
        float m_p1 = m_use;

        // 16-deep register prefetch pipeline over featsT[t][b][:]
        v2f ebuf[PDEPTH][3];
#define ISSUE(slot, tt) do {                                              \
        const v2f* _p = (const v2f*)(base + (size_t)(tt) * (NB * NVT));   \
        ebuf[slot][0] = _p[0]; ebuf[slot][1] = _p[1]; ebuf[slot][2] = _p[2]; \
    } while (0)

#pragma unroll
        for (int u = 0; u < PDEPTH; ++u) ISSUE(u, 1 + u);

        int t = 1;
        for (int c = 0; c < NT / PDEPTH; ++c) {   // 32 chunks -> t = 1..512
#pragma unroll
            for (int u = 0; u < PDEPTH; ++u) {
                // consume slot u, then reissue for t+PDEPTH (clamped)
                float e0 = ebuf[u][0].x, e1 = ebuf[u][0].y,
                      e2 = ebuf[u][1].x, e3 = ebuf[u][1].y,
                      e4 = ebuf[u][2].x, e5 = ebuf[u][2].y;
                int tn = t + PDEPTH; if (tn > NT - 1) tn = NT - 1;
                ISSUE(u, tn);

                float mc = m_use * LOG2E;
                float p0 = __builtin_amdgcn_exp2f(__builtin_fmaf(a[0], LOG2E, -mc));
                float p1 = __builtin_amdgcn_exp2f(__builtin_fmaf(a[1], LOG2E, -mc));
                float p2 = __builtin_amdgcn_exp2f(__builtin_fmaf(a[2], LOG2E, -mc));
                float p3 = __builtin_amdgcn_exp2f(__builtin_fmaf(a[3], LOG2E, -mc));
                float p4 = __builtin_amdgcn_exp2f(__builtin_fmaf(a[4], LOG2E, -mc));
                float p5 = __builtin_amdgcn_exp2f(__builtin_fmaf(a[5], LOG2E, -mc));
                v2f s2[3];
#pragma unroll
                for (int jh = 0; jh < 3; ++jh) {
                    v2f u01 = __builtin_elementwise_fma((v2f){p1, p1}, F2[1][jh],
                                                        ((v2f){p0, p0}) * F2[0][jh]);
                    v2f u23 = __builtin_elementwise_fma((v2f){p3, p3}, F2[3][jh],
                                                        ((v2f){p2, p2}) * F2[2][jh]);
                    v2f u45 = __builtin_elementwise_fma((v2f){p5, p5}, F2[5][jh],
                                                        ((v2f){p4, p4}) * F2[4][jh]);
                    s2[jh] = (u01 + u23) + u45;
                }
                // fold m + e_j off the critical path
                float me0 = m_use + e0, me1 = m_use + e1, me2 = m_use + e2;
                float me3 = m_use + e3, me4 = m_use + e4, me5 = m_use + e5;
                float n0 = __builtin_fmaf(__builtin_amdgcn_logf(s2[0].x), LN2, me0);
                float n1 = __builtin_fmaf(__builtin_amdgcn_logf(s2[0].y), LN2, me1);
                float n2 = __builtin_fmaf(__builtin_amdgcn_logf(s2[1].x), LN2, me2);
                float n3 = __builtin_fmaf(__builtin_amdgcn_logf(s2[1].y), LN2, me3);
                float n4 = __builtin_fmaf(__builtin_amdgcn_logf(s2[2].x), LN2, me4);
                float n5 = __builtin_fmaf(__builtin_amdgcn_logf(s2[2].y), LN2, me5);
                bool ok = t < L;
                a[0] = ok ? n0 : a[0];
                a[1] = ok ? n1 : a[1];
                a[2] = ok ? n2 : a[2];
                a[3] = ok ? n3 : a[3];
                a[4] = ok ? n4 : a[4];
                a[5] = ok ? n5 : a[5];
                // 2-stale max: tree runs off the critical path
                m_use = m_p1;
                m_p1 = fmaxf(fmaxf(fmaxf(a[0], a[1]), a[2]),
                             fmaxf(fmaxf(a[3], a[4]), a[5]));
                ++t;
            }
        }
#undef ISSUE

        float z[NVT];
#pragma unroll
        for (int j = 0; j < NVT; ++j) z[j] = a[j] + crf_end[j];
        float m = fmaxf(fmaxf(fmaxf(z[0], z[1]), z[2]),
                        fmaxf(fmaxf(z[3], z[4]), z[5]));
        float sum = 0.0f;
#pragma unroll
        for (int j = 0; j < NVT; ++j)
            sum += __builtin_amdgcn_exp2f((z[j] - m) * LOG2E);
        float logZ = __builtin_fmaf(__builtin_amdgcn_logf(sum), LN2, m);
        atomicAdd(&out[b], logZ);
    } else if (blockIdx.x <= NB) {
        // ---------- gold path score: one wave per sample, lanes over t ----------
        const int b = blockIdx.x - 1;
        for (int i = lane; i < NT; i += 64) stag[i] = tag_ids[b * NT + i];
        if (lane < NVT * NVT) trL[lane] = crf_trans[lane];
        __syncthreads();
        const int L = seq_lens[b];
        float g = 0.0f;
#pragma unroll
        for (int k = 0; k < NT / 64; ++k) {
            int t = lane + 64 * k;
            if (t < L) {
                int tg = stag[t];
                g += featsT[((size_t)t * NB + b) * NVT + tg];
                if (t >= 1) g += trL[stag[t - 1] * NVT + tg];
            }
        }
#pragma unroll
        for (int off = 32; off >= 1; off >>= 1) g += __shfl_xor(g, off);
        if (lane == 0)
            atomicAdd(&out[b], -(g + crf_start[stag[0]] + crf_end[stag[L - 1]]));
    } else {
        // ---------- entity path: one wave per entity ----------
        const int e  = blockIdx.x - NB - 1;
        const int b  = ent_sid[e];
        const int s  = ent_st[e];
        const int en = ent_en[e];
        const int ty = ent_ty[e];
        float4 sv[4];
#pragma unroll
        for (int k = 0; k < 4; ++k) { sv[k].x = 0.f; sv[k].y = 0.f; sv[k].z = 0.f; sv[k].w = 0.f; }
        for (int t = s; t < en; ++t) {
            const float4* hr = (const float4*)(H + ((size_t)b * NT + t) * ND);
#pragma unroll
            for (int k = 0; k < 4; ++k) {
                float4 h = hr[lane + 64 * k];
                sv[k].x += h.x; sv[k].y += h.y; sv[k].z += h.z; sv[k].w += h.w;
            }
        }
        const float inv = 1.0f / (float)(en - s);
        float f[NVY];
#pragma unroll
        for (int v = 0; v < NVY; ++v) {
            const float4* wv = (const float4*)(WtT + v * ND);
            float p = 0.0f;
#pragma unroll
            for (int k = 0; k < 4; ++k) {
                float4 w = wv[lane + 64 * k];
                p += sv[k].x * w.x + sv[k].y * w.y + sv[k].z * w.z + sv[k].w * w.w;
            }
#pragma unroll
            for (int off = 32; off >= 1; off >>= 1) p += __shfl_xor(p, off);
            f[v] = p * inv + b_type[v];
        }
        float mx = -3.0e38f;
#pragma unroll
        for (int v = 0; v < NVY; ++v) mx = fmaxf(mx, f[v]);
        float sum = 0.0f, goldf = 0.0f;
#pragma unroll
        for (int v = 0; v < NVY; ++v) {
            sum += __expf(f[v] - mx);
            if (v == ty) goldf = f[v];
        }
        float lse = mx + __logf(sum);
        if (ty != TYPE_PAD_V && lane == 0) atomicAdd(&out[b], lse - goldf);
    }
}

extern "C" void kernel_launch(void* const* d_in, const int* in_sizes, int n_in,
                              void* d_out, int out_size, void* d_ws, size_t ws_size,
                              hipStream_t stream) {
    const float* H         = (const float*)d_in[0];
    const float* W_tag     = (const float*)d_in[1];
    const float* b_tag     = (const float*)d_in[2];
    const float* W_type    = (const float*)d_in[3];
    const float* b_type    = (const float*)d_in[4];
    const float* crf_start = (const float*)d_in[5];
    const float* crf_end   = (const float*)d_in[6];
    const float* crf_trans = (const float*)d_in[7];
    const int* tag_ids     = (const int*)d_in[8];
    const int* seq_lens    = (const int*)d_in[9];
    const int* ent_sid     = (const int*)d_in[10];
    const int* ent_st      = (const int*)d_in[11];
    const int* ent_en      = (const int*)d_in[12];
    const int* ent_ty      = (const int*)d_in[13];
    float* out = (float*)d_out;
    float* ws  = (float*)d_ws;
    float* featsT = ws;                              // [T][B][6] = 196608 floats
    float* WtT    = ws + (size_t)NB * NT * NVT;      // [20][1024] = 20480 floats

    hipLaunchKernelGGL(k0_prep, dim3(32), dim3(256), 0, stream, W_type, WtT, out);
    hipLaunchKernelGGL(k1_tagfeats, dim3(1024), dim3(256), 0, stream, H, W_tag, b_tag, featsT);
    hipLaunchKernelGGL(k2_fused, dim3(1 + NB + NE), dim3(64), 0, stream,
                       featsT, WtT, H, b_type, crf_start, crf_end, crf_trans,
                       tag_ids, seq_lens, ent_sid, ent_st, ent_en, ent_ty, out);
}

// Round 5
// 83.615 us; speedup vs baseline: 4.4101x; 1.5130x over previous
//
#include <hip/hip_runtime.h>
#include <math.h>
#include <stdint.h>

#define NB  64
#define NT  512
#define ND  1024
#define NVT 6
#define NVY 20
#define TYPE_PAD_V 19
#define NE  2048
#define LOG2E 1.44269504088896340736f
#define LN2   0.69314718055994530942f

#define ESTRIDE_B 2048               // bytes per step in featsE (512 words; 2x dma16)
#define RING_B    (16 * ESTRIDE_B)   // 32768 B LDS ring (16 steps)
#define GROUP_B   (4 * ESTRIDE_B)    // 8192: 4-slot group
#define WRAP_B    (3 * GROUP_B)      // 24576

typedef float v2f __attribute__((ext_vector_type(2)));

__device__ __forceinline__ void dma16(const void* g, void* l) {
    __builtin_amdgcn_global_load_lds((const __attribute__((address_space(1))) uint32_t*)g,
                                     (__attribute__((address_space(3))) uint32_t*)l, 16, 0, 0);
}

// ---------------- K0: transpose W_type into ws, zero d_out ----------------
__global__ __launch_bounds__(256) void k0_prep(const float* __restrict__ W_type,
                                               float* __restrict__ WtT,
                                               float* __restrict__ out) {
    if (blockIdx.x == 0 && threadIdx.x < NB) out[threadIdx.x] = 0.0f;
    int tid = blockIdx.x * 256 + threadIdx.x;
    int stride = gridDim.x * 256;
    for (int i = tid; i < NVY * ND; i += stride) {
        int v = i >> 10;
        int d = i & (ND - 1);
        WtT[i] = W_type[d * NVY + v];
    }
}

// ---- K1: featsT raw [t][b][6]  +  featsE = exp(feats), 512-word swizzled stride ----
__global__ __launch_bounds__(256) void k1_tagfeats(const float* __restrict__ H,
                                                   const float* __restrict__ W_tag,
                                                   const float* __restrict__ b_tag,
                                                   float* __restrict__ featsT,
                                                   float* __restrict__ featsE) {
    __shared__ float wlds[NVT][ND];
    for (int i = threadIdx.x; i < ND * NVT; i += 256) {
        int d = i / NVT, v = i % NVT;
        wlds[v][d] = W_tag[i];
    }
    __syncthreads();
    float bt[NVT];
#pragma unroll
    for (int v = 0; v < NVT; ++v) bt[v] = b_tag[v];

    const int lane = threadIdx.x & 63;
    const int wid  = threadIdx.x >> 6;
    const int qw   = lane >> 4;
    const int ql   = lane & 15;
    const int rowBase = blockIdx.x * 32;

#pragma unroll
    for (int it = 0; it < 2; ++it) {
        const int r = rowBase + it * 16 + wid * 4 + qw;
        const float4* hrow = (const float4*)(H + (size_t)r * ND);
        float acc[NVT] = {0.f, 0.f, 0.f, 0.f, 0.f, 0.f};
#pragma unroll
        for (int k = 0; k < 16; ++k) {
            float4 h = hrow[ql + 16 * k];
#pragma unroll
            for (int v = 0; v < NVT; ++v) {
                float4 w = ((const float4*)&wlds[v][0])[ql + 16 * k];
                acc[v] += h.x * w.x + h.y * w.y + h.z * w.z + h.w * w.w;
            }
        }
#pragma unroll
        for (int v = 0; v < NVT; ++v) {
#pragma unroll
            for (int off = 8; off >= 1; off >>= 1)
                acc[v] += __shfl_xor(acc[v], off);
        }
        const int bb = r >> 9;
        const int tt = r & (NT - 1);
#pragma unroll
        for (int v = 0; v < NVT; ++v)
            if (ql == v) {
                float val = acc[v] + bt[v];
                featsT[(size_t)tt * 384 + bb * 6 + v] = val;
                featsE[(size_t)tt * 512 + bb * 6 + 2 * (bb >> 4) + v] =
                    __builtin_amdgcn_exp2f(val * LOG2E);
            }
    }
}

// ---------------- K2: fused scan(block 0) + gold(1..64) + entities(65..) ----------------
#define SCAN_STEP(E3, tcur) do {                                             \
    float q0=qv[0].x, q1=qv[0].y, q2=qv[1].x, q3=qv[1].y, q4=qv[2].x, q5=qv[2].y; \
    v2f sa, sb, sc;                                                          \
    sa = ((v2f){q0,q0}) * F2[0][0];                                          \
    sb = ((v2f){q0,q0}) * F2[0][1];                                          \
    sc = ((v2f){q0,q0}) * F2[0][2];                                          \
    sa = __builtin_elementwise_fma((v2f){q1,q1}, F2[1][0], sa);              \
    sb = __builtin_elementwise_fma((v2f){q1,q1}, F2[1][1], sb);              \
    sc = __builtin_elementwise_fma((v2f){q1,q1}, F2[1][2], sc);              \
    sa = __builtin_elementwise_fma((v2f){q2,q2}, F2[2][0], sa);              \
    sb = __builtin_elementwise_fma((v2f){q2,q2}, F2[2][1], sb);              \
    sc = __builtin_elementwise_fma((v2f){q2,q2}, F2[2][2], sc);              \
    sa = __builtin_elementwise_fma((v2f){q3,q3}, F2[3][0], sa);              \
    sb = __builtin_elementwise_fma((v2f){q3,q3}, F2[3][1], sb);              \
    sc = __builtin_elementwise_fma((v2f){q3,q3}, F2[3][2], sc);              \
    sa = __builtin_elementwise_fma((v2f){q4,q4}, F2[4][0], sa);              \
    sb = __builtin_elementwise_fma((v2f){q4,q4}, F2[4][1], sb);              \
    sc = __builtin_elementwise_fma((v2f){q4,q4}, F2[4][2], sc);              \
    sa = __builtin_elementwise_fma((v2f){q5,q5}, F2[5][0], sa);              \
    sb = __builtin_elementwise_fma((v2f){q5,q5}, F2[5][1], sb);              \
    sc = __builtin_elementwise_fma((v2f){q5,q5}, F2[5][2], sc);              \
    sa = sa * (E3)[0]; sb = sb * (E3)[1]; sc = sc * (E3)[2];                 \
    bool ok = (tcur) < L;                                                    \
    qv[0].x = ok ? sa.x : qv[0].x;  qv[0].y = ok ? sa.y : qv[0].y;           \
    qv[1].x = ok ? sb.x : qv[1].x;  qv[1].y = ok ? sb.y : qv[1].y;           \
    qv[2].x = ok ? sc.x : qv[2].x;  qv[2].y = ok ? sc.y : qv[2].y;           \
} while (0)

#define RESCALE() do {                                                       \
    v2f mm = __builtin_elementwise_max(qv[0], qv[1]);                        \
    mm = __builtin_elementwise_max(mm, qv[2]);                               \
    float qmax = fmaxf(mm.x, mm.y);                                          \
    float ri = __builtin_amdgcn_rcpf(qmax);                                  \
    qv[0] = qv[0] * ((v2f){ri, ri});                                         \
    qv[1] = qv[1] * ((v2f){ri, ri});                                         \
    qv[2] = qv[2] * ((v2f){ri, ri});                                         \
    mAcc += __builtin_amdgcn_logf(qmax);                                     \
} while (0)

#define SCAN_BODY(RCUR, RNEXT) do {                                          \
    asm volatile("s_waitcnt vmcnt(8)" ::: "memory");                         \
    __builtin_amdgcn_sched_barrier(0);                                       \
    _Pragma("unroll")                                                        \
    for (int k = 0; k < 4; ++k) {                                            \
        int s = gs + k; s = s > 511 ? 511 : s;                               \
        const char* g = efc + (size_t)s * ESTRIDE_B;                         \
        char* l = ringw + db + k * ESTRIDE_B;                                \
        dma16(g + l16, l);                                                   \
        dma16(g + 1024 + l16, l + 1024);                                     \
    }                                                                        \
    _Pragma("unroll")                                                        \
    for (int k = 0; k < 4; ++k) {                                            \
        const v2f* p = (const v2f*)(ringc + rb + k * ESTRIDE_B + rdoff);     \
        RNEXT[k][0] = p[0]; RNEXT[k][1] = p[1]; RNEXT[k][2] = p[2];          \
    }                                                                        \
    _Pragma("unroll")                                                        \
    for (int k = 0; k < 4; ++k) { SCAN_STEP(RCUR[k], t0 + k); }              \
    RESCALE();                                                               \
    t0 += 4;                                                                 \
    gs += 4;                                                                 \
    rb = (rb == WRAP_B) ? 0 : rb + GROUP_B;                                  \
    db = (db == WRAP_B) ? 0 : db + GROUP_B;                                  \
} while (0)

__global__ __launch_bounds__(64) void k2_fused(
    const float* __restrict__ featsT,
    const float* __restrict__ featsE,
    const float* __restrict__ WtT,
    const float* __restrict__ H,
    const float* __restrict__ b_type,
    const float* __restrict__ crf_start,
    const float* __restrict__ crf_end,
    const float* __restrict__ crf_trans,
    const int* __restrict__ tag_ids,
    const int* __restrict__ seq_lens,
    const int* __restrict__ ent_sid,
    const int* __restrict__ ent_st,
    const int* __restrict__ ent_en,
    const int* __restrict__ ent_ty,
    float* __restrict__ out) {
    __shared__ __align__(16) float smemf[RING_B / 4];   // 32768 B: scan ring / gold scratch
    const int lane = threadIdx.x;

    if (blockIdx.x == 0) {
        // ---------- forward scan in exp-domain: lane = sample ----------
        const int b = lane;
        const int L = seq_lens[b];
        v2f F2[NVT][3];
#pragma unroll
        for (int i = 0; i < NVT; ++i)
#pragma unroll
            for (int h = 0; h < 3; ++h) {
                F2[i][h].x = __builtin_amdgcn_exp2f(crf_trans[i * NVT + 2 * h] * LOG2E);
                F2[i][h].y = __builtin_amdgcn_exp2f(crf_trans[i * NVT + 2 * h + 1] * LOG2E);
            }
        float Eend[NVT];
#pragma unroll
        for (int j = 0; j < NVT; ++j) Eend[j] = __builtin_amdgcn_exp2f(crf_end[j] * LOG2E);
        float a0[NVT];
#pragma unroll
        for (int j = 0; j < NVT; ++j) a0[j] = crf_start[j] + featsT[b * NVT + j];
        float m0 = fmaxf(fmaxf(fmaxf(a0[0], a0[1]), a0[2]),
                         fmaxf(fmaxf(a0[3], a0[4]), a0[5]));
        v2f qv[3];
#pragma unroll
        for (int h = 0; h < 3; ++h) {
            qv[h].x = __builtin_amdgcn_exp2f((a0[2 * h] - m0) * LOG2E);
            qv[h].y = __builtin_amdgcn_exp2f((a0[2 * h + 1] - m0) * LOG2E);
        }
        float mAcc = m0 * LOG2E;   // running shift in log2 units

        const char* ringc = (const char*)smemf;
        char* ringw = (char*)smemf;
        const char* efc = (const char*)featsE;
        const int rdoff = lane * 24 + (lane >> 4) * 8;  // byte off: word lane*6+2*(lane>>4)
        const int l16 = lane * 16;

        asm volatile("s_waitcnt vmcnt(0)" ::: "memory");
        // prologue: DMA steps 1..12 (24 ops, 2 per step)
#pragma unroll
        for (int s = 1; s <= 12; ++s) {
            const char* g = efc + (size_t)s * ESTRIDE_B;
            char* l = ringw + ((s - 1) & 15) * ESTRIDE_B;
            dma16(g + l16, l);
            dma16(g + 1024 + l16, l + 1024);
        }
        asm volatile("s_waitcnt vmcnt(16)" ::: "memory");  // steps 1..4 landed
        __builtin_amdgcn_sched_barrier(0);

        v2f rA[4][3], rB[4][3];
#pragma unroll
        for (int k = 0; k < 4; ++k) {
            const v2f* p = (const v2f*)(ringc + k * ESTRIDE_B + rdoff);
            rA[k][0] = p[0]; rA[k][1] = p[1]; rA[k][2] = p[2];
        }

        int t0 = 1;
        int rb = GROUP_B;           // read base: slots of steps 5..8
        int gs = 13;                // next DMA step
        int db = 3 * GROUP_B;       // DMA dest base: slot of step 13
#pragma unroll 1
        for (int cc = 0; cc < 63; ++cc) {
            SCAN_BODY(rA, rB);
            SCAN_BODY(rB, rA);
        }
        SCAN_BODY(rA, rB);          // body 127: computes 505..508, reads 509..511(+dup)
        SCAN_STEP(rB[0], 509);
        SCAN_STEP(rB[1], 510);
        SCAN_STEP(rB[2], 511);

        float zs = qv[0].x * Eend[0] + qv[0].y * Eend[1] + qv[1].x * Eend[2]
                 + qv[1].y * Eend[3] + qv[2].x * Eend[4] + qv[2].y * Eend[5];
        float logZ = LN2 * (mAcc + __builtin_amdgcn_logf(zs));
        atomicAdd(&out[b], logZ);
    } else if (blockIdx.x <= NB) {
        // ---------- gold path score: one wave per sample, lanes over t ----------
        const int b = blockIdx.x - 1;
        int* stag = (int*)smemf;
        float* trLp = smemf + 512;
        for (int i = lane; i < NT; i += 64) stag[i] = tag_ids[b * NT + i];
        if (lane < NVT * NVT) trLp[lane] = crf_trans[lane];
        __syncthreads();
        const int L = seq_lens[b];
        float g = 0.0f;
#pragma unroll
        for (int k = 0; k < NT / 64; ++k) {
            int t = lane + 64 * k;
            if (t < L) {
                int tg = stag[t];
                g += featsT[(size_t)t * 384 + b * 6 + tg];
                if (t >= 1) g += trLp[stag[t - 1] * NVT + tg];
            }
        }
#pragma unroll
        for (int off = 32; off >= 1; off >>= 1) g += __shfl_xor(g, off);
        if (lane == 0)
            atomicAdd(&out[b], -(g + crf_start[stag[0]] + crf_end[stag[L - 1]]));
    } else {
        // ---------- entity path: one wave per entity ----------
        const int e  = blockIdx.x - NB - 1;
        const int bb = ent_sid[e];
        const int s  = ent_st[e];
        const int en = ent_en[e];
        const int ty = ent_ty[e];
        float4 sv[4];
#pragma unroll
        for (int k = 0; k < 4; ++k) { sv[k].x = 0.f; sv[k].y = 0.f; sv[k].z = 0.f; sv[k].w = 0.f; }
        for (int t = s; t < en; ++t) {
            const float4* hr = (const float4*)(H + ((size_t)bb * NT + t) * ND);
#pragma unroll
            for (int k = 0; k < 4; ++k) {
                float4 h = hr[lane + 64 * k];
                sv[k].x += h.x; sv[k].y += h.y; sv[k].z += h.z; sv[k].w += h.w;
            }
        }
        const float inv = 1.0f / (float)(en - s);
        float f[NVY];
#pragma unroll
        for (int v = 0; v < NVY; ++v) {
            const float4* wv = (const float4*)(WtT + v * ND);
            float p = 0.0f;
#pragma unroll
            for (int k = 0; k < 4; ++k) {
                float4 w = wv[lane + 64 * k];
                p += sv[k].x * w.x + sv[k].y * w.y + sv[k].z * w.z + sv[k].w * w.w;
            }
#pragma unroll
            for (int off = 32; off >= 1; off >>= 1) p += __shfl_xor(p, off);
            f[v] = p * inv + b_type[v];
        }
        float mx = -3.0e38f;
#pragma unroll
        for (int v = 0; v < NVY; ++v) mx = fmaxf(mx, f[v]);
        float sum = 0.0f, goldf = 0.0f;
#pragma unroll
        for (int v = 0; v < NVY; ++v) {
            sum += __expf(f[v] - mx);
            if (v == ty) goldf = f[v];
        }
        float lse = mx + __logf(sum);
        if (ty != TYPE_PAD_V && lane == 0) atomicAdd(&out[bb], lse - goldf);
    }
}

extern "C" void kernel_launch(void* const* d_in, const int* in_sizes, int n_in,
                              void* d_out, int out_size, void* d_ws, size_t ws_size,
                              hipStream_t stream) {
    const float* H         = (const float*)d_in[0];
    const float* W_tag     = (const float*)d_in[1];
    const float* b_tag     = (const float*)d_in[2];
    const float* W_type    = (const float*)d_in[3];
    const float* b_type    = (const float*)d_in[4];
    const float* crf_start = (const float*)d_in[5];
    const float* crf_end   = (const float*)d_in[6];
    const float* crf_trans = (const float*)d_in[7];
    const int* tag_ids     = (const int*)d_in[8];
    const int* seq_lens    = (const int*)d_in[9];
    const int* ent_sid     = (const int*)d_in[10];
    const int* ent_st      = (const int*)d_in[11];
    const int* ent_en      = (const int*)d_in[12];
    const int* ent_ty      = (const int*)d_in[13];
    float* out = (float*)d_out;
    float* ws  = (float*)d_ws;
    float* featsE = ws;                        // 512*512 = 262144 floats (swizzled exp)
    float* featsT = ws + 262144;               // 512*384 = 196608 floats (raw)
    float* WtT    = ws + 262144 + 196608;      // 20*1024 = 20480 floats

    hipLaunchKernelGGL(k0_prep, dim3(32), dim3(256), 0, stream, W_type, WtT, out);
    hipLaunchKernelGGL(k1_tagfeats, dim3(1024), dim3(256), 0, stream,
                       H, W_tag, b_tag, featsT, featsE);
    hipLaunchKernelGGL(k2_fused, dim3(1 + NB + NE), dim3(64), 0, stream,
                       featsT, featsE, WtT, H, b_type, crf_start, crf_end, crf_trans,
                       tag_ids, seq_lens, ent_sid, ent_st, ent_en, ent_ty, out);
}

// Round 7
// 62.768 us; speedup vs baseline: 5.8748x; 1.3321x over previous
//
#include <hip/hip_runtime.h>
#include <math.h>
#include <stdint.h>

#define NB  64
#define NT  512
#define ND  1024
#define NVT 6
#define NVY 20
#define TYPE_PAD_V 19
#define NE  2048
#define LOG2E 1.44269504088896340736f
#define LN2   0.69314718055994530942f

typedef float v2f __attribute__((ext_vector_type(2)));

// ---- K1: featsT raw [t][b][6]  +  featsE = exp(feats), 512-word stride ----
__global__ __launch_bounds__(256) void k1_tagfeats(const float* __restrict__ H,
                                                   const float* __restrict__ W_tag,
                                                   const float* __restrict__ b_tag,
                                                   float* __restrict__ featsT,
                                                   float* __restrict__ featsE) {
    __shared__ float wlds[NVT][ND];
    for (int i = threadIdx.x; i < ND * NVT; i += 256) {
        int d = i / NVT, v = i % NVT;
        wlds[v][d] = W_tag[i];
    }
    __syncthreads();
    float bt[NVT];
#pragma unroll
    for (int v = 0; v < NVT; ++v) bt[v] = b_tag[v];

    const int lane = threadIdx.x & 63;
    const int wid  = threadIdx.x >> 6;
    const int qw   = lane >> 4;
    const int ql   = lane & 15;
    const int rowBase = blockIdx.x * 32;

#pragma unroll
    for (int it = 0; it < 2; ++it) {
        const int r = rowBase + it * 16 + wid * 4 + qw;
        const float4* hrow = (const float4*)(H + (size_t)r * ND);
        float acc[NVT] = {0.f, 0.f, 0.f, 0.f, 0.f, 0.f};
#pragma unroll
        for (int k = 0; k < 16; ++k) {
            float4 h = hrow[ql + 16 * k];
#pragma unroll
            for (int v = 0; v < NVT; ++v) {
                float4 w = ((const float4*)&wlds[v][0])[ql + 16 * k];
                acc[v] += h.x * w.x + h.y * w.y + h.z * w.z + h.w * w.w;
            }
        }
#pragma unroll
        for (int v = 0; v < NVT; ++v) {
#pragma unroll
            for (int off = 8; off >= 1; off >>= 1)
                acc[v] += __shfl_xor(acc[v], off);
        }
        const int bb = r >> 9;
        const int tt = r & (NT - 1);
#pragma unroll
        for (int v = 0; v < NVT; ++v)
            if (ql == v) {
                float val = acc[v] + bt[v];
                featsT[(size_t)tt * 384 + bb * 6 + v] = val;
                featsE[(size_t)tt * 512 + bb * 6 + 2 * (bb >> 4) + v] =
                    __builtin_amdgcn_exp2f(val * LOG2E);
            }
    }
}

// ---- K2a: per-(chunk c, column k) block, lane = sample b.
//      Computes column k of P_c = prod_{t in chunk} diag(E_t) F^T  (masked steps = I)
//      with exact power-of-2 rescaling. Also: W_type transpose + out zero.
__global__ __launch_bounds__(64) void k2a_chunks(
    const float* __restrict__ featsE,
    const float* __restrict__ crf_trans,
    const int* __restrict__ seq_lens,
    const float* __restrict__ W_type,
    float* __restrict__ WtT,
    float* __restrict__ out,
    float* __restrict__ ws2) {
    const int c = blockIdx.x / 6;
    const int k = blockIdx.x - 6 * c;
    const int b = threadIdx.x;
    // side work: zero out, transpose W_type (runs before k2 in stream order)
    if (blockIdx.x == 0) out[b] = 0.0f;
    {
        int tid = blockIdx.x * 64 + b;
        for (int i = tid; i < NVY * ND; i += 192 * 64)
            WtT[i] = W_type[(i & (ND - 1)) * NVY + (i >> 10)];
    }
    const int L = seq_lens[b];
    float F[NVT][NVT];
#pragma unroll
    for (int i = 0; i < NVT; ++i)
#pragma unroll
        for (int j = 0; j < NVT; ++j)
            F[i][j] = __builtin_amdgcn_exp2f(crf_trans[i * NVT + j] * LOG2E);
    // preload the 16 E-rows of this chunk (row t=512 maps into featsT: valid mem, masked)
    const char* pl = (const char*)featsE + b * 24 + (b >> 4) * 8;
    v2f Ebuf[16][3];
#pragma unroll
    for (int u = 0; u < 16; ++u) {
        const v2f* p = (const v2f*)(pl + (size_t)(16 * c + 1 + u) * 2048);
        Ebuf[u][0] = p[0]; Ebuf[u][1] = p[1]; Ebuf[u][2] = p[2];
    }
    float v0, v1, v2, v3, v4, v5;
    v0 = (k == 0) ? 1.f : 0.f; v1 = (k == 1) ? 1.f : 0.f; v2 = (k == 2) ? 1.f : 0.f;
    v3 = (k == 3) ? 1.f : 0.f; v4 = (k == 4) ? 1.f : 0.f; v5 = (k == 5) ? 1.f : 0.f;
    int isc = 0;
#pragma unroll
    for (int u = 0; u < 16; ++u) {
        float e0 = Ebuf[u][0].x, e1 = Ebuf[u][0].y, e2 = Ebuf[u][1].x,
              e3 = Ebuf[u][1].y, e4 = Ebuf[u][2].x, e5 = Ebuf[u][2].y;
        bool ok = (16 * c + 1 + u) < L;
        float g[NVT];
#pragma unroll
        for (int j = 0; j < NVT; ++j) {
            float s = F[0][j] * v0;
            s = __builtin_fmaf(F[1][j], v1, s);
            s = __builtin_fmaf(F[2][j], v2, s);
            s = __builtin_fmaf(F[3][j], v3, s);
            s = __builtin_fmaf(F[4][j], v4, s);
            s = __builtin_fmaf(F[5][j], v5, s);
            g[j] = s;
        }
        v0 = ok ? e0 * g[0] : v0;  v1 = ok ? e1 * g[1] : v1;
        v2 = ok ? e2 * g[2] : v2;  v3 = ok ? e3 * g[3] : v3;
        v4 = ok ? e4 * g[4] : v4;  v5 = ok ? e5 * g[5] : v5;
        if ((u & 3) == 3) {   // exact power-of-2 rescale
            float qmax = fmaxf(fmaxf(fmaxf(v0, v1), v2), fmaxf(fmaxf(v3, v4), v5));
            uint32_t eb = __float_as_uint(qmax) >> 23;
            float ri = __uint_as_float((uint32_t)(253 - eb) << 23);
            v0 *= ri; v1 *= ri; v2 *= ri; v3 *= ri; v4 *= ri; v5 *= ri;
            isc += (int)eb - 126;
        }
    }
    float4* dst = (float4*)(ws2 + (((size_t)c * 6 + k) * 64 + b) * 8);
    dst[0] = make_float4(v0, v1, v2, v3);
    dst[1] = make_float4(v4, v5, (float)isc, 0.0f);
}

// ---- K2: combine(block 0) + gold(1..64) + entities(65..) ----
#define LOADC(BUF, c) do {                                                   \
    _Pragma("unroll")                                                        \
    for (int kk = 0; kk < 6; ++kk) {                                         \
        const float4* p = src4 + (size_t)((c) * 6 + kk) * 128;               \
        BUF[2 * kk] = p[0]; BUF[2 * kk + 1] = p[1];                          \
    }                                                                        \
} while (0)

#define CBODY(BUF, c) do {                                                   \
    float i0 = BUF[1].z, i1 = BUF[3].z, i2 = BUF[5].z,                       \
          i3 = BUF[7].z, i4 = BUF[9].z, i5 = BUF[11].z;                      \
    float im = fmaxf(fmaxf(fmaxf(i0, i1), i2), fmaxf(fmaxf(i3, i4), i5));    \
    float w0 = q0 * __builtin_amdgcn_exp2f(i0 - im);                         \
    float w1 = q1 * __builtin_amdgcn_exp2f(i1 - im);                         \
    float w2 = q2 * __builtin_amdgcn_exp2f(i2 - im);                         \
    float w3 = q3 * __builtin_amdgcn_exp2f(i3 - im);                         \
    float w4 = q4 * __builtin_amdgcn_exp2f(i4 - im);                         \
    float w5 = q5 * __builtin_amdgcn_exp2f(i5 - im);                         \
    float n0 = BUF[0].x * w0, n1 = BUF[0].y * w0, n2 = BUF[0].z * w0,        \
          n3 = BUF[0].w * w0, n4 = BUF[1].x * w0, n5 = BUF[1].y * w0;        \
    n0 = __builtin_fmaf(BUF[2].x,  w1, n0); n1 = __builtin_fmaf(BUF[2].y,  w1, n1); \
    n2 = __builtin_fmaf(BUF[2].z,  w1, n2); n3 = __builtin_fmaf(BUF[2].w,  w1, n3); \
    n4 = __builtin_fmaf(BUF[3].x,  w1, n4); n5 = __builtin_fmaf(BUF[3].y,  w1, n5); \
    n0 = __builtin_fmaf(BUF[4].x,  w2, n0); n1 = __builtin_fmaf(BUF[4].y,  w2, n1); \
    n2 = __builtin_fmaf(BUF[4].z,  w2, n2); n3 = __builtin_fmaf(BUF[4].w,  w2, n3); \
    n4 = __builtin_fmaf(BUF[5].x,  w2, n4); n5 = __builtin_fmaf(BUF[5].y,  w2, n5); \
    n0 = __builtin_fmaf(BUF[6].x,  w3, n0); n1 = __builtin_fmaf(BUF[6].y,  w3, n1); \
    n2 = __builtin_fmaf(BUF[6].z,  w3, n2); n3 = __builtin_fmaf(BUF[6].w,  w3, n3); \
    n4 = __builtin_fmaf(BUF[7].x,  w3, n4); n5 = __builtin_fmaf(BUF[7].y,  w3, n5); \
    n0 = __builtin_fmaf(BUF[8].x,  w4, n0); n1 = __builtin_fmaf(BUF[8].y,  w4, n1); \
    n2 = __builtin_fmaf(BUF[8].z,  w4, n2); n3 = __builtin_fmaf(BUF[8].w,  w4, n3); \
    n4 = __builtin_fmaf(BUF[9].x,  w4, n4); n5 = __builtin_fmaf(BUF[9].y,  w4, n5); \
    n0 = __builtin_fmaf(BUF[10].x, w5, n0); n1 = __builtin_fmaf(BUF[10].y, w5, n1); \
    n2 = __builtin_fmaf(BUF[10].z, w5, n2); n3 = __builtin_fmaf(BUF[10].w, w5, n3); \
    n4 = __builtin_fmaf(BUF[11].x, w5, n4); n5 = __builtin_fmaf(BUF[11].y, w5, n5); \
    float qmax = fmaxf(fmaxf(fmaxf(n0, n1), n2), fmaxf(fmaxf(n3, n4), n5));  \
    uint32_t eb = __float_as_uint(qmax) >> 23;                               \
    mAcc2 += (float)((int)eb - 126) + im;                                    \
    float ri = __uint_as_float((uint32_t)(253 - eb) << 23);                  \
    q0 = n0 * ri; q1 = n1 * ri; q2 = n2 * ri;                                \
    q3 = n3 * ri; q4 = n4 * ri; q5 = n5 * ri;                                \
    int lc = (c) + 3; if (lc > 31) lc = 31;                                  \
    LOADC(BUF, lc);                                                          \
} while (0)

__global__ __launch_bounds__(64) void k2_fused(
    const float* __restrict__ featsT,
    const float* __restrict__ ws2,
    const float* __restrict__ WtT,
    const float* __restrict__ H,
    const float* __restrict__ b_type,
    const float* __restrict__ crf_start,
    const float* __restrict__ crf_end,
    const float* __restrict__ crf_trans,
    const int* __restrict__ tag_ids,
    const int* __restrict__ seq_lens,
    const int* __restrict__ ent_sid,
    const int* __restrict__ ent_st,
    const int* __restrict__ ent_en,
    const int* __restrict__ ent_ty,
    float* __restrict__ out) {
    __shared__ int stag[NT];
    __shared__ float trLp[NVT * NVT];
    const int lane = threadIdx.x;

    if (blockIdx.x == 0) {
        // ---------- combine: lane = sample, 32 chunk matvecs ----------
        const int b = lane;
        float a0[NVT];
#pragma unroll
        for (int j = 0; j < NVT; ++j) a0[j] = crf_start[j] + featsT[b * 6 + j];
        float m0 = fmaxf(fmaxf(fmaxf(a0[0], a0[1]), a0[2]),
                         fmaxf(fmaxf(a0[3], a0[4]), a0[5]));
        float q0 = __builtin_amdgcn_exp2f((a0[0] - m0) * LOG2E);
        float q1 = __builtin_amdgcn_exp2f((a0[1] - m0) * LOG2E);
        float q2 = __builtin_amdgcn_exp2f((a0[2] - m0) * LOG2E);
        float q3 = __builtin_amdgcn_exp2f((a0[3] - m0) * LOG2E);
        float q4 = __builtin_amdgcn_exp2f((a0[4] - m0) * LOG2E);
        float q5 = __builtin_amdgcn_exp2f((a0[5] - m0) * LOG2E);
        float mAcc2 = m0 * LOG2E;   // log2 units

        const float4* src4 = (const float4*)ws2 + b * 2;
        float4 PB0[12], PB1[12], PB2[12];
        LOADC(PB0, 0); LOADC(PB1, 1); LOADC(PB2, 2);
#pragma unroll 1
        for (int c0 = 0; c0 < 30; c0 += 3) {
            CBODY(PB0, c0);
            CBODY(PB1, c0 + 1);
            CBODY(PB2, c0 + 2);
        }
        CBODY(PB0, 30);
        CBODY(PB1, 31);

        float fe0 = __builtin_amdgcn_exp2f(crf_end[0] * LOG2E);
        float fe1 = __builtin_amdgcn_exp2f(crf_end[1] * LOG2E);
        float fe2 = __builtin_amdgcn_exp2f(crf_end[2] * LOG2E);
        float fe3 = __builtin_amdgcn_exp2f(crf_end[3] * LOG2E);
        float fe4 = __builtin_amdgcn_exp2f(crf_end[4] * LOG2E);
        float fe5 = __builtin_amdgcn_exp2f(crf_end[5] * LOG2E);
        float zs = q0 * fe0 + q1 * fe1 + q2 * fe2 + q3 * fe3 + q4 * fe4 + q5 * fe5;
        float logZ = LN2 * (mAcc2 + __builtin_amdgcn_logf(zs));
        atomicAdd(&out[b], logZ);
    } else if (blockIdx.x <= NB) {
        // ---------- gold path score: one wave per sample, lanes over t ----------
        const int b = blockIdx.x - 1;
        for (int i = lane; i < NT; i += 64) stag[i] = tag_ids[b * NT + i];
        if (lane < NVT * NVT) trLp[lane] = crf_trans[lane];
        __syncthreads();
        const int L = seq_lens[b];
        float g = 0.0f;
#pragma unroll
        for (int k = 0; k < NT / 64; ++k) {
            int t = lane + 64 * k;
            if (t < L) {
                int tg = stag[t];
                g += featsT[(size_t)t * 384 + b * 6 + tg];
                if (t >= 1) g += trLp[stag[t - 1] * NVT + tg];
            }
        }
#pragma unroll
        for (int off = 32; off >= 1; off >>= 1) g += __shfl_xor(g, off);
        if (lane == 0)
            atomicAdd(&out[b], -(g + crf_start[stag[0]] + crf_end[stag[L - 1]]));
    } else {
        // ---------- entity path: one wave per entity ----------
        const int e  = blockIdx.x - NB - 1;
        const int bb = ent_sid[e];
        const int s  = ent_st[e];
        const int en = ent_en[e];
        const int ty = ent_ty[e];
        float4 sv[4];
#pragma unroll
        for (int k = 0; k < 4; ++k) { sv[k].x = 0.f; sv[k].y = 0.f; sv[k].z = 0.f; sv[k].w = 0.f; }
        for (int t = s; t < en; ++t) {
            const float4* hr = (const float4*)(H + ((size_t)bb * NT + t) * ND);
#pragma unroll
            for (int k = 0; k < 4; ++k) {
                float4 h = hr[lane + 64 * k];
                sv[k].x += h.x; sv[k].y += h.y; sv[k].z += h.z; sv[k].w += h.w;
            }
        }
        const float inv = 1.0f / (float)(en - s);
        float f[NVY];
#pragma unroll
        for (int v = 0; v < NVY; ++v) {
            const float4* wv = (const float4*)(WtT + v * ND);
            float p = 0.0f;
#pragma unroll
            for (int k = 0; k < 4; ++k) {
                float4 w = wv[lane + 64 * k];
                p += sv[k].x * w.x + sv[k].y * w.y + sv[k].z * w.z + sv[k].w * w.w;
            }
#pragma unroll
            for (int off = 32; off >= 1; off >>= 1) p += __shfl_xor(p, off);
            f[v] = p * inv + b_type[v];
        }
        float mx = -3.0e38f;
#pragma unroll
        for (int v = 0; v < NVY; ++v) mx = fmaxf(mx, f[v]);
        float sum = 0.0f, goldf = 0.0f;
#pragma unroll
        for (int v = 0; v < NVY; ++v) {
            sum += __expf(f[v] - mx);
            if (v == ty) goldf = f[v];
        }
        float lse = mx + __logf(sum);
        if (ty != TYPE_PAD_V && lane == 0) atomicAdd(&out[bb], lse - goldf);
    }
}

extern "C" void kernel_launch(void* const* d_in, const int* in_sizes, int n_in,
                              void* d_out, int out_size, void* d_ws, size_t ws_size,
                              hipStream_t stream) {
    const float* H         = (const float*)d_in[0];
    const float* W_tag     = (const float*)d_in[1];
    const float* b_tag     = (const float*)d_in[2];
    const float* W_type    = (const float*)d_in[3];
    const float* b_type    = (const float*)d_in[4];
    const float* crf_start = (const float*)d_in[5];
    const float* crf_end   = (const float*)d_in[6];
    const float* crf_trans = (const float*)d_in[7];
    const int* tag_ids     = (const int*)d_in[8];
    const int* seq_lens    = (const int*)d_in[9];
    const int* ent_sid     = (const int*)d_in[10];
    const int* ent_st      = (const int*)d_in[11];
    const int* ent_en      = (const int*)d_in[12];
    const int* ent_ty      = (const int*)d_in[13];
    float* out = (float*)d_out;
    float* ws  = (float*)d_ws;
    float* featsE = ws;                                  // 512*512 floats
    float* featsT = ws + 262144;                         // 512*384 floats (+dummy row)
    float* WtT    = ws + 262144 + 196608;                // 20480 floats
    float* ws2    = ws + 262144 + 196608 + 20480;        // 32*6*64*8 = 98304 floats

    hipLaunchKernelGGL(k1_tagfeats, dim3(1024), dim3(256), 0, stream,
                       H, W_tag, b_tag, featsT, featsE);
    hipLaunchKernelGGL(k2a_chunks, dim3(192), dim3(64), 0, stream,
                       featsE, crf_trans, seq_lens, W_type, WtT, out, ws2);
    hipLaunchKernelGGL(k2_fused, dim3(1 + NB + NE), dim3(64), 0, stream,
                       featsT, ws2, WtT, H, b_type, crf_start, crf_end, crf_trans,
                       tag_ids, seq_lens, ent_sid, ent_st, ent_en, ent_ty, out);
}

// Round 8
// 61.440 us; speedup vs baseline: 6.0018x; 1.0216x over previous
//
#include <hip/hip_runtime.h>
#include <math.h>
#include <stdint.h>

#define NB  64
#define NT  512
#define ND  1024
#define NVT 6
#define NVY 20
#define TYPE_PAD_V 19
#define NE  2048
#define LOG2E 1.44269504088896340736f
#define LN2   0.69314718055994530942f

typedef float v2f __attribute__((ext_vector_type(2)));

// ws layout (floats):
//   featsT @ 0        : 512*384 = 196608   [t][b][6]
//   WtT    @ 196608   : 20*1024 = 20480    [v][d]
//   cnt    @ 217088   : 16 (counter + pad)
//   ws2    @ 217104   : 32*6*64*8 = 98304  chunk columns
#define OFF_WTT 196608
#define OFF_CNT 217088
#define OFF_WS2 217104

// ---- K1: featsT = H @ W_tag + b_tag  (+ side: WtT transpose, zero out/cnt) ----
__global__ __launch_bounds__(256) void k1_tagfeats(const float* __restrict__ H,
                                                   const float* __restrict__ W_tag,
                                                   const float* __restrict__ b_tag,
                                                   const float* __restrict__ W_type,
                                                   float* __restrict__ ws,
                                                   float* __restrict__ out) {
    float* featsT = ws;
    float* WtT    = ws + OFF_WTT;
    // side work: zero out + counter (block 0), transpose W_type (blocks 0..31)
    if (blockIdx.x == 0) {
        if (threadIdx.x < NB) out[threadIdx.x] = 0.0f;
        if (threadIdx.x == 64) ((int*)(ws + OFF_CNT))[0] = 0;
    }
    if (blockIdx.x < 32) {
        int tid = blockIdx.x * 256 + threadIdx.x;
        for (int i = tid; i < NVY * ND; i += 32 * 256)
            WtT[i] = W_type[(i & (ND - 1)) * NVY + (i >> 10)];
    }

    __shared__ float wlds[NVT][ND];
    for (int i = threadIdx.x; i < ND * NVT; i += 256) {
        int d = i / NVT, v = i % NVT;
        wlds[v][d] = W_tag[i];
    }
    __syncthreads();
    float bt[NVT];
#pragma unroll
    for (int v = 0; v < NVT; ++v) bt[v] = b_tag[v];

    const int lane = threadIdx.x & 63;
    const int wid  = threadIdx.x >> 6;
    const int qw   = lane >> 4;
    const int ql   = lane & 15;
    const int rowBase = blockIdx.x * 32;

#pragma unroll
    for (int it = 0; it < 2; ++it) {
        const int r = rowBase + it * 16 + wid * 4 + qw;
        const float4* hrow = (const float4*)(H + (size_t)r * ND);
        float acc[NVT] = {0.f, 0.f, 0.f, 0.f, 0.f, 0.f};
#pragma unroll
        for (int k = 0; k < 16; ++k) {
            float4 h = hrow[ql + 16 * k];
#pragma unroll
            for (int v = 0; v < NVT; ++v) {
                float4 w = ((const float4*)&wlds[v][0])[ql + 16 * k];
                acc[v] += h.x * w.x + h.y * w.y + h.z * w.z + h.w * w.w;
            }
        }
#pragma unroll
        for (int v = 0; v < NVT; ++v) {
#pragma unroll
            for (int off = 8; off >= 1; off >>= 1)
                acc[v] += __shfl_xor(acc[v], off);
        }
        const int bb = r >> 9;
        const int tt = r & (NT - 1);
#pragma unroll
        for (int v = 0; v < NVT; ++v)
            if (ql == v) featsT[(size_t)tt * 384 + bb * 6 + v] = acc[v] + bt[v];
    }
}

// ---- K2: chunks(0..191, fan-in combine) + gold(192..255) + entities(256..) ----
#define LOADC(BUF, c) do {                                                   \
    _Pragma("unroll")                                                        \
    for (int kk = 0; kk < 6; ++kk) {                                         \
        const float4* p = src4 + (size_t)((c) * 6 + kk) * 128;               \
        BUF[2 * kk] = p[0]; BUF[2 * kk + 1] = p[1];                          \
    }                                                                        \
} while (0)

#define CBODY(BUF, c) do {                                                   \
    float i0 = BUF[1].z, i1 = BUF[3].z, i2 = BUF[5].z,                       \
          i3 = BUF[7].z, i4 = BUF[9].z, i5 = BUF[11].z;                      \
    float im = fmaxf(fmaxf(fmaxf(i0, i1), i2), fmaxf(fmaxf(i3, i4), i5));    \
    float w0 = q0 * __builtin_amdgcn_exp2f(i0 - im);                         \
    float w1 = q1 * __builtin_amdgcn_exp2f(i1 - im);                         \
    float w2 = q2 * __builtin_amdgcn_exp2f(i2 - im);                         \
    float w3 = q3 * __builtin_amdgcn_exp2f(i3 - im);                         \
    float w4 = q4 * __builtin_amdgcn_exp2f(i4 - im);                         \
    float w5 = q5 * __builtin_amdgcn_exp2f(i5 - im);                         \
    float n0 = BUF[0].x * w0, n1 = BUF[0].y * w0, n2 = BUF[0].z * w0,        \
          n3 = BUF[0].w * w0, n4 = BUF[1].x * w0, n5 = BUF[1].y * w0;        \
    n0 = __builtin_fmaf(BUF[2].x,  w1, n0); n1 = __builtin_fmaf(BUF[2].y,  w1, n1); \
    n2 = __builtin_fmaf(BUF[2].z,  w1, n2); n3 = __builtin_fmaf(BUF[2].w,  w1, n3); \
    n4 = __builtin_fmaf(BUF[3].x,  w1, n4); n5 = __builtin_fmaf(BUF[3].y,  w1, n5); \
    n0 = __builtin_fmaf(BUF[4].x,  w2, n0); n1 = __builtin_fmaf(BUF[4].y,  w2, n1); \
    n2 = __builtin_fmaf(BUF[4].z,  w2, n2); n3 = __builtin_fmaf(BUF[4].w,  w2, n3); \
    n4 = __builtin_fmaf(BUF[5].x,  w2, n4); n5 = __builtin_fmaf(BUF[5].y,  w2, n5); \
    n0 = __builtin_fmaf(BUF[6].x,  w3, n0); n1 = __builtin_fmaf(BUF[6].y,  w3, n1); \
    n2 = __builtin_fmaf(BUF[6].z,  w3, n2); n3 = __builtin_fmaf(BUF[6].w,  w3, n3); \
    n4 = __builtin_fmaf(BUF[7].x,  w3, n4); n5 = __builtin_fmaf(BUF[7].y,  w3, n5); \
    n0 = __builtin_fmaf(BUF[8].x,  w4, n0); n1 = __builtin_fmaf(BUF[8].y,  w4, n1); \
    n2 = __builtin_fmaf(BUF[8].z,  w4, n2); n3 = __builtin_fmaf(BUF[8].w,  w4, n3); \
    n4 = __builtin_fmaf(BUF[9].x,  w4, n4); n5 = __builtin_fmaf(BUF[9].y,  w4, n5); \
    n0 = __builtin_fmaf(BUF[10].x, w5, n0); n1 = __builtin_fmaf(BUF[10].y, w5, n1); \
    n2 = __builtin_fmaf(BUF[10].z, w5, n2); n3 = __builtin_fmaf(BUF[10].w, w5, n3); \
    n4 = __builtin_fmaf(BUF[11].x, w5, n4); n5 = __builtin_fmaf(BUF[11].y, w5, n5); \
    float qmax = fmaxf(fmaxf(fmaxf(n0, n1), n2), fmaxf(fmaxf(n3, n4), n5));  \
    uint32_t eb = __float_as_uint(qmax) >> 23;                               \
    mAcc2 += (float)((int)eb - 126) + im;                                    \
    float ri = __uint_as_float((uint32_t)(253 - eb) << 23);                  \
    q0 = n0 * ri; q1 = n1 * ri; q2 = n2 * ri;                                \
    q3 = n3 * ri; q4 = n4 * ri; q5 = n5 * ri;                                \
    int lc = (c) + 3; if (lc > 31) lc = 31;                                  \
    LOADC(BUF, lc);                                                          \
} while (0)

__global__ __launch_bounds__(64) void k2_fused(
    const float* __restrict__ H,
    const float* __restrict__ b_type,
    const float* __restrict__ crf_start,
    const float* __restrict__ crf_end,
    const float* __restrict__ crf_trans,
    const int* __restrict__ tag_ids,
    const int* __restrict__ seq_lens,
    const int* __restrict__ ent_sid,
    const int* __restrict__ ent_st,
    const int* __restrict__ ent_en,
    const int* __restrict__ ent_ty,
    float* __restrict__ ws,
    float* __restrict__ out) {
    const float* featsT = ws;
    const float* WtT    = ws + OFF_WTT;
    int* cnt            = (int*)(ws + OFF_CNT);
    float* ws2          = ws + OFF_WS2;
    __shared__ int stag[NT];
    __shared__ float trLp[NVT * NVT];
    __shared__ int isLast;
    const int lane = threadIdx.x;

    if (blockIdx.x < 192) {
        // ---------- chunk block: column k of P_c, lane = sample b ----------
        const int c = blockIdx.x / 6;
        const int k = blockIdx.x - 6 * c;
        const int b = lane;
        const int L = seq_lens[b];
        float F[NVT][NVT];
#pragma unroll
        for (int i = 0; i < NVT; ++i)
#pragma unroll
            for (int j = 0; j < NVT; ++j)
                F[i][j] = __builtin_amdgcn_exp2f(crf_trans[i * NVT + j] * LOG2E);
        const char* pf = (const char*)featsT + b * 24;
        v2f Ebuf[16][3];
#pragma unroll
        for (int u = 0; u < 16; ++u) {
            const v2f* p = (const v2f*)(pf + (size_t)(16 * c + 1 + u) * 1536);
            Ebuf[u][0] = p[0]; Ebuf[u][1] = p[1]; Ebuf[u][2] = p[2];
        }
        float v0, v1, v2, v3, v4, v5;
        v0 = (k == 0) ? 1.f : 0.f; v1 = (k == 1) ? 1.f : 0.f; v2 = (k == 2) ? 1.f : 0.f;
        v3 = (k == 3) ? 1.f : 0.f; v4 = (k == 4) ? 1.f : 0.f; v5 = (k == 5) ? 1.f : 0.f;
        int isc = 0;
#pragma unroll
        for (int u = 0; u < 16; ++u) {
            float e0 = __builtin_amdgcn_exp2f(Ebuf[u][0].x * LOG2E);
            float e1 = __builtin_amdgcn_exp2f(Ebuf[u][0].y * LOG2E);
            float e2 = __builtin_amdgcn_exp2f(Ebuf[u][1].x * LOG2E);
            float e3 = __builtin_amdgcn_exp2f(Ebuf[u][1].y * LOG2E);
            float e4 = __builtin_amdgcn_exp2f(Ebuf[u][2].x * LOG2E);
            float e5 = __builtin_amdgcn_exp2f(Ebuf[u][2].y * LOG2E);
            bool ok = (16 * c + 1 + u) < L;
            float g[NVT];
#pragma unroll
            for (int j = 0; j < NVT; ++j) {
                float s = F[0][j] * v0;
                s = __builtin_fmaf(F[1][j], v1, s);
                s = __builtin_fmaf(F[2][j], v2, s);
                s = __builtin_fmaf(F[3][j], v3, s);
                s = __builtin_fmaf(F[4][j], v4, s);
                s = __builtin_fmaf(F[5][j], v5, s);
                g[j] = s;
            }
            v0 = ok ? e0 * g[0] : v0;  v1 = ok ? e1 * g[1] : v1;
            v2 = ok ? e2 * g[2] : v2;  v3 = ok ? e3 * g[3] : v3;
            v4 = ok ? e4 * g[4] : v4;  v5 = ok ? e5 * g[5] : v5;
            if ((u & 3) == 3) {   // exact power-of-2 rescale
                float qmax = fmaxf(fmaxf(fmaxf(v0, v1), v2), fmaxf(fmaxf(v3, v4), v5));
                uint32_t eb = __float_as_uint(qmax) >> 23;
                float ri = __uint_as_float((uint32_t)(253 - eb) << 23);
                v0 *= ri; v1 *= ri; v2 *= ri; v3 *= ri; v4 *= ri; v5 *= ri;
                isc += (int)eb - 126;
            }
        }
        float4* dst = (float4*)(ws2 + (((size_t)c * 6 + k) * 64 + b) * 8);
        dst[0] = make_float4(v0, v1, v2, v3);
        dst[1] = make_float4(v4, v5, (float)isc, 0.0f);

        // ---- fan-in: last chunk block performs the combine ----
        __threadfence();
        if (lane == 0) isLast = (atomicAdd(cnt, 1) == 191);
        __syncthreads();
        if (isLast) {
            __threadfence();   // acquire: other blocks' ws2 writes now visible
            const int b2 = lane;
            float a0[NVT];
#pragma unroll
            for (int j = 0; j < NVT; ++j) a0[j] = crf_start[j] + featsT[b2 * 6 + j];
            float m0 = fmaxf(fmaxf(fmaxf(a0[0], a0[1]), a0[2]),
                             fmaxf(fmaxf(a0[3], a0[4]), a0[5]));
            float q0 = __builtin_amdgcn_exp2f((a0[0] - m0) * LOG2E);
            float q1 = __builtin_amdgcn_exp2f((a0[1] - m0) * LOG2E);
            float q2 = __builtin_amdgcn_exp2f((a0[2] - m0) * LOG2E);
            float q3 = __builtin_amdgcn_exp2f((a0[3] - m0) * LOG2E);
            float q4 = __builtin_amdgcn_exp2f((a0[4] - m0) * LOG2E);
            float q5 = __builtin_amdgcn_exp2f((a0[5] - m0) * LOG2E);
            float mAcc2 = m0 * LOG2E;

            const float4* src4 = (const float4*)ws2 + b2 * 2;
            float4 PB0[12], PB1[12], PB2[12];
            LOADC(PB0, 0); LOADC(PB1, 1); LOADC(PB2, 2);
#pragma unroll 1
            for (int c0 = 0; c0 < 30; c0 += 3) {
                CBODY(PB0, c0);
                CBODY(PB1, c0 + 1);
                CBODY(PB2, c0 + 2);
            }
            CBODY(PB0, 30);
            CBODY(PB1, 31);

            float zs = q0 * __builtin_amdgcn_exp2f(crf_end[0] * LOG2E)
                     + q1 * __builtin_amdgcn_exp2f(crf_end[1] * LOG2E)
                     + q2 * __builtin_amdgcn_exp2f(crf_end[2] * LOG2E)
                     + q3 * __builtin_amdgcn_exp2f(crf_end[3] * LOG2E)
                     + q4 * __builtin_amdgcn_exp2f(crf_end[4] * LOG2E)
                     + q5 * __builtin_amdgcn_exp2f(crf_end[5] * LOG2E);
            float logZ = LN2 * (mAcc2 + __builtin_amdgcn_logf(zs));
            atomicAdd(&out[b2], logZ);
        }
    } else if (blockIdx.x < 192 + NB) {
        // ---------- gold path score: one wave per sample, lanes over t ----------
        const int b = blockIdx.x - 192;
        for (int i = lane; i < NT; i += 64) stag[i] = tag_ids[b * NT + i];
        if (lane < NVT * NVT) trLp[lane] = crf_trans[lane];
        __syncthreads();
        const int L = seq_lens[b];
        float g = 0.0f;
#pragma unroll
        for (int k = 0; k < NT / 64; ++k) {
            int t = lane + 64 * k;
            if (t < L) {
                int tg = stag[t];
                g += featsT[(size_t)t * 384 + b * 6 + tg];
                if (t >= 1) g += trLp[stag[t - 1] * NVT + tg];
            }
        }
#pragma unroll
        for (int off = 32; off >= 1; off >>= 1) g += __shfl_xor(g, off);
        if (lane == 0)
            atomicAdd(&out[b], -(g + crf_start[stag[0]] + crf_end[stag[L - 1]]));
    } else {
        // ---------- entity path: one wave per entity ----------
        const int e  = blockIdx.x - 192 - NB;
        const int bb = ent_sid[e];
        const int s  = ent_st[e];
        const int en = ent_en[e];
        const int ty = ent_ty[e];
        float4 sv[4];
#pragma unroll
        for (int k = 0; k < 4; ++k) { sv[k].x = 0.f; sv[k].y = 0.f; sv[k].z = 0.f; sv[k].w = 0.f; }
        for (int t = s; t < en; ++t) {
            const float4* hr = (const float4*)(H + ((size_t)bb * NT + t) * ND);
#pragma unroll
            for (int k = 0; k < 4; ++k) {
                float4 h = hr[lane + 64 * k];
                sv[k].x += h.x; sv[k].y += h.y; sv[k].z += h.z; sv[k].w += h.w;
            }
        }
        const float inv = 1.0f / (float)(en - s);
        float f[NVY];
#pragma unroll
        for (int v = 0; v < NVY; ++v) {
            const float4* wv = (const float4*)(WtT + v * ND);
            float p = 0.0f;
#pragma unroll
            for (int k = 0; k < 4; ++k) {
                float4 w = wv[lane + 64 * k];
                p += sv[k].x * w.x + sv[k].y * w.y + sv[k].z * w.z + sv[k].w * w.w;
            }
#pragma unroll
            for (int off = 32; off >= 1; off >>= 1) p += __shfl_xor(p, off);
            f[v] = p * inv + b_type[v];
        }
        float mx = -3.0e38f;
#pragma unroll
        for (int v = 0; v < NVY; ++v) mx = fmaxf(mx, f[v]);
        float sum = 0.0f, goldf = 0.0f;
#pragma unroll
        for (int v = 0; v < NVY; ++v) {
            sum += __expf(f[v] - mx);
            if (v == ty) goldf = f[v];
        }
        float lse = mx + __logf(sum);
        if (ty != TYPE_PAD_V && lane == 0) atomicAdd(&out[bb], lse - goldf);
    }
}

extern "C" void kernel_launch(void* const* d_in, const int* in_sizes, int n_in,
                              void* d_out, int out_size, void* d_ws, size_t ws_size,
                              hipStream_t stream) {
    const float* H         = (const float*)d_in[0];
    const float* W_tag     = (const float*)d_in[1];
    const float* b_tag     = (const float*)d_in[2];
    const float* W_type    = (const float*)d_in[3];
    const float* b_type    = (const float*)d_in[4];
    const float* crf_start = (const float*)d_in[5];
    const float* crf_end   = (const float*)d_in[6];
    const float* crf_trans = (const float*)d_in[7];
    const int* tag_ids     = (const int*)d_in[8];
    const int* seq_lens    = (const int*)d_in[9];
    const int* ent_sid     = (const int*)d_in[10];
    const int* ent_st      = (const int*)d_in[11];
    const int* ent_en      = (const int*)d_in[12];
    const int* ent_ty      = (const int*)d_in[13];
    float* out = (float*)d_out;
    float* ws  = (float*)d_ws;

    hipLaunchKernelGGL(k1_tagfeats, dim3(1024), dim3(256), 0, stream,
                       H, W_tag, b_tag, W_type, ws, out);
    hipLaunchKernelGGL(k2_fused, dim3(192 + NB + NE), dim3(64), 0, stream,
                       H, b_type, crf_start, crf_end, crf_trans,
                       tag_ids, seq_lens, ent_sid, ent_st, ent_en, ent_ty, ws, out);
}